// Round 1
// baseline (79.403 us; speedup 1.0000x reference)
//
#include <hip/hip_runtime.h>
#include <math.h>

// ActELoss: loss = sum_{b,i,j} exp(-|a0[b,i]-p0[b,i+j]|/2) * |a2[b,i]-p2[b,i+j]|
//           + 0.1 * sum_b ||a0[b,:]-a2[b,:]||_2
// p = padded row: 6 copies of first, row, 5 copies of last (len T+11).
// B=4096, T=750, W=11. Output: scalar fp32.

#define T_LEN 750
#define W_LEN 11
#define PAD_T 761          // T + 11
#define BLK 256
#define CPT 3              // consecutive positions per thread; 250 active threads
#define WIN (CPT + 10)     // register window size per thread per array

__global__ __launch_bounds__(BLK) void actloss_partial(
    const float* __restrict__ a0, const float* __restrict__ a2,
    float* __restrict__ partials)
{
    __shared__ float s0[PAD_T];
    __shared__ float s2[PAD_T];

    const int b   = blockIdx.x;
    const int tid = threadIdx.x;
    const float* __restrict__ g0 = a0 + (size_t)b * T_LEN;
    const float* __restrict__ g2 = a2 + (size_t)b * T_LEN;

    // Stage padded row into LDS: s[k] = row[clamp(k-6, 0, T-1)]
    for (int k = tid; k < PAD_T; k += BLK) {
        int src = k - 6;
        src = src < 0 ? 0 : (src > T_LEN - 1 ? T_LEN - 1 : src);
        s0[k] = g0[src];
        s2[k] = g2[src];
    }
    __syncthreads();

    float loss = 0.0f;
    float sq   = 0.0f;

    if (tid < T_LEN / CPT) {           // 250 active
        const int i0 = tid * CPT;
        float r0[WIN], r2[WIN];
#pragma unroll
        for (int k = 0; k < WIN; ++k) {
            r0[k] = s0[i0 + k];        // padded idx i0+k ; compiler merges adjacents
            r2[k] = s2[i0 + k];
        }
#pragma unroll
        for (int ci = 0; ci < CPT; ++ci) {
            const float c0 = r0[ci + 6];   // = a0[b, i0+ci]
            const float c2 = r2[ci + 6];   // = a2[b, i0+ci]
#pragma unroll
            for (int j = 0; j < W_LEN; ++j) {
                // exp(-|d0|/2): v_sub + v_mul(abs mod) + v_exp
                const float wv = __expf(-0.5f * fabsf(c0 - r0[ci + j]));
                loss = fmaf(wv, fabsf(c2 - r2[ci + j]), loss);
            }
            const float d = c0 - c2;
            sq = fmaf(d, d, sq);
        }
    }

    // wave64 shuffle reduce
#pragma unroll
    for (int off = 32; off > 0; off >>= 1) {
        loss += __shfl_down(loss, off, 64);
        sq   += __shfl_down(sq,   off, 64);
    }
    __shared__ float rl[BLK / 64], rs[BLK / 64];
    const int wid  = tid >> 6;
    const int lane = tid & 63;
    if (lane == 0) { rl[wid] = loss; rs[wid] = sq; }
    __syncthreads();
    if (tid == 0) {
        float L = 0.0f, S = 0.0f;
#pragma unroll
        for (int w = 0; w < BLK / 64; ++w) { L += rl[w]; S += rs[w]; }
        partials[b] = L + 0.1f * sqrtf(S);
    }
}

__global__ __launch_bounds__(BLK) void actloss_final(
    const float* __restrict__ partials, int n, float* __restrict__ out)
{
    float v = 0.0f;
    for (int k = threadIdx.x; k < n; k += BLK) v += partials[k];
#pragma unroll
    for (int off = 32; off > 0; off >>= 1) v += __shfl_down(v, off, 64);
    __shared__ float r[BLK / 64];
    const int wid  = threadIdx.x >> 6;
    const int lane = threadIdx.x & 63;
    if (lane == 0) r[wid] = v;
    __syncthreads();
    if (threadIdx.x == 0) {
        float s = 0.0f;
#pragma unroll
        for (int w = 0; w < BLK / 64; ++w) s += r[w];
        out[0] = s;   // E_ALPHA = 1.0
    }
}

extern "C" void kernel_launch(void* const* d_in, const int* in_sizes, int n_in,
                              void* d_out, int out_size, void* d_ws, size_t ws_size,
                              hipStream_t stream)
{
    const float* a0 = (const float*)d_in[0];
    const float* a2 = (const float*)d_in[1];
    float* out      = (float*)d_out;
    float* partials = (float*)d_ws;                 // B floats, fully overwritten
    const int B = in_sizes[0] / T_LEN;              // 4096

    actloss_partial<<<B, BLK, 0, stream>>>(a0, a2, partials);
    actloss_final<<<1, BLK, 0, stream>>>(partials, B, out);
}

// Round 2
// 77.433 us; speedup vs baseline: 1.0254x; 1.0254x over previous
//
#include <hip/hip_runtime.h>
#include <math.h>

// ActELoss, symmetric reformulation.
// S = sum_{b,i,j=0..10} exp(-|a0[i]-p0[i+j]|/2)*|a2[i]-p2[i+j]|, p = pad(6 first,5 last)
// Using symmetry f(i,m)=f(m,i) and f(i,i)=0:
//   S = sum_{k=1..4} 2*sum_{i=0}^{749-k} f(i,i+k)
//     + sum_{k=5..6}   sum_{i=0}^{749-k} f(i,i+k)
//     + sum_{i=1..5} (6-i) f(i,0)            (left clamp extras)
//     + sum_{i=746..748} (i-745) f(i,749)    (right clamp extras)
// plus 0.1 * sum_b ||a0-a2||_2.

#define T_LEN 750
#define BLK   256
#define CPT   3            // positions per thread; 250 active threads
#define NACT  (T_LEN / CPT)
#define SPAD  756          // staged length: need reads up to i0+8 = 755
#define L2E_HALF 0.72134752044f   // 0.5 * log2(e)

__global__ __launch_bounds__(BLK) void actloss_partial(
    const float* __restrict__ a0, const float* __restrict__ a2,
    float* __restrict__ partials)
{
    __shared__ float s0[SPAD];
    __shared__ float s2[SPAD];

    const int b   = blockIdx.x;
    const int tid = threadIdx.x;
    const float* __restrict__ g0 = a0 + (size_t)b * T_LEN;
    const float* __restrict__ g2 = a2 + (size_t)b * T_LEN;

    // Stage raw row; indices >= 750 replicate last element (masked anyway,
    // replication just keeps values finite).
    for (int k = tid; k < SPAD; k += BLK) {
        const int src = k < T_LEN ? k : T_LEN - 1;
        s0[k] = g0[src];
        s2[k] = g2[src];
    }
    __syncthreads();

    float loss1 = 0.0f;   // weight-1 terms (k=5,6 and edge extras)
    float loss2 = 0.0f;   // weight-2 terms (k=1..4)
    float sq    = 0.0f;

    if (tid < NACT) {
        const int i0 = tid * CPT;
        float r0[CPT + 6], r2[CPT + 6];
#pragma unroll
        for (int k = 0; k < CPT + 6; ++k) {
            r0[k] = s0[i0 + k];
            r2[k] = s2[i0 + k];
        }
#pragma unroll
        for (int ci = 0; ci < CPT; ++ci) {
            const float c0 = r0[ci];
            const float c2 = r2[ci];
#pragma unroll
            for (int k = 1; k <= 6; ++k) {
                const float wv  = __builtin_amdgcn_exp2f(
                                      -L2E_HALF * fabsf(c0 - r0[ci + k]));
                float ad2 = fabsf(c2 - r2[ci + k]);
                ad2 = (i0 + ci + k < T_LEN) ? ad2 : 0.0f;   // drop out-of-range pairs
                if (k <= 4) loss2 = fmaf(wv, ad2, loss2);
                else        loss1 = fmaf(wv, ad2, loss1);
            }
            const float d = c0 - c2;
            sq = fmaf(d, d, sq);
        }
    } else if (tid == NACT) {
        // clamp edge extras (8 terms)
#pragma unroll
        for (int i = 1; i <= 5; ++i) {
            const float wv = __builtin_amdgcn_exp2f(-L2E_HALF * fabsf(s0[i] - s0[0]));
            loss1 = fmaf(wv * (float)(6 - i), fabsf(s2[i] - s2[0]), loss1);
        }
#pragma unroll
        for (int i = 746; i <= 748; ++i) {
            const float wv = __builtin_amdgcn_exp2f(-L2E_HALF * fabsf(s0[i] - s0[T_LEN - 1]));
            loss1 = fmaf(wv * (float)(i - 745), fabsf(s2[i] - s2[T_LEN - 1]), loss1);
        }
    }

    float loss = fmaf(2.0f, loss2, loss1);

    // wave64 shuffle reduce
#pragma unroll
    for (int off = 32; off > 0; off >>= 1) {
        loss += __shfl_down(loss, off, 64);
        sq   += __shfl_down(sq,   off, 64);
    }
    __shared__ float rl[BLK / 64], rs[BLK / 64];
    const int wid  = tid >> 6;
    const int lane = tid & 63;
    if (lane == 0) { rl[wid] = loss; rs[wid] = sq; }
    __syncthreads();
    if (tid == 0) {
        float L = 0.0f, S = 0.0f;
#pragma unroll
        for (int w = 0; w < BLK / 64; ++w) { L += rl[w]; S += rs[w]; }
        partials[b] = L + 0.1f * sqrtf(S);
    }
}

__global__ __launch_bounds__(BLK) void actloss_final(
    const float* __restrict__ partials, int n, float* __restrict__ out)
{
    float v = 0.0f;
    for (int k = threadIdx.x; k < n; k += BLK) v += partials[k];
#pragma unroll
    for (int off = 32; off > 0; off >>= 1) v += __shfl_down(v, off, 64);
    __shared__ float r[BLK / 64];
    if ((threadIdx.x & 63) == 0) r[threadIdx.x >> 6] = v;
    __syncthreads();
    if (threadIdx.x == 0) {
        float s = 0.0f;
#pragma unroll
        for (int w = 0; w < BLK / 64; ++w) s += r[w];
        out[0] = s;
    }
}

extern "C" void kernel_launch(void* const* d_in, const int* in_sizes, int n_in,
                              void* d_out, int out_size, void* d_ws, size_t ws_size,
                              hipStream_t stream)
{
    const float* a0 = (const float*)d_in[0];
    const float* a2 = (const float*)d_in[1];
    float* out      = (float*)d_out;
    float* partials = (float*)d_ws;              // B floats, fully overwritten
    const int B = in_sizes[0] / T_LEN;           // 4096

    actloss_partial<<<B, BLK, 0, stream>>>(a0, a2, partials);
    actloss_final<<<1, BLK, 0, stream>>>(partials, B, out);
}